// Round 8
// baseline (211.602 us; speedup 1.0000x reference)
//
#include <hip/hip_runtime.h>
#include <math.h>

#define B 8
#define NSMI 100
#define NATOM 45
#define ND 145      // NSMI + NATOM
#define NP 1000
#define D 64
#define NROW 1145   // ND + NP rows per batch

#define PROJ_RPB 16
#define PROJ_BPB 72          // ceil(1145/16)
#define ROW_BPB 37           // ceil(145/4)   rowsum blocks per batch (4 i's each)
#define COL_BPB 250          // 1000/4        colsum blocks per batch (4 j's each)
#define PAIR_ROW_BLKS (B * ROW_BPB)            // 296
#define PAIR_BLKS (PAIR_ROW_BLKS + B * COL_BPB) // 2296
#define TAIL_BLKS 256        // 1 block/CU on 256 CUs; all co-resident

__device__ __forceinline__ float4 f4z() { float4 z; z.x = z.y = z.z = z.w = 0.f; return z; }
__device__ __forceinline__ void f4acc(float4& a, const float4& v) {
    a.x += v.x; a.y += v.y; a.z += v.z; a.w += v.w;
}
__device__ __forceinline__ void acc_relu(float4& acc, const float4& a, const float4& p) {
    acc.x += fmaxf(0.f, a.x + p.x);
    acc.y += fmaxf(0.f, a.y + p.y);
    acc.z += fmaxf(0.f, a.z + p.z);
    acc.w += fmaxf(0.f, a.w + p.w);
}
__device__ __forceinline__ void wave_red_g(float4& v) {
    v.x += __shfl_xor(v.x, 16, 64); v.x += __shfl_xor(v.x, 32, 64);
    v.y += __shfl_xor(v.y, 16, 64); v.y += __shfl_xor(v.y, 32, 64);
    v.z += __shfl_xor(v.z, 16, 64); v.z += __shfl_xor(v.z, 32, 64);
    v.w += __shfl_xor(v.w, 16, 64); v.w += __shfl_xor(v.w, 32, 64);
}

// device-scope grid barrier (TAIL_BLKS = 256 blocks = 1/CU, co-resident)
__device__ __forceinline__ void gridbar(int* bar, int ph, int nblk) {
    __syncthreads();
    if (threadIdx.x == 0) {
        __threadfence();
        __hip_atomic_fetch_add(&bar[ph], 1, __ATOMIC_ACQ_REL, __HIP_MEMORY_SCOPE_AGENT);
        while (__hip_atomic_load(&bar[ph], __ATOMIC_ACQUIRE, __HIP_MEMORY_SCOPE_AGENT) < nblk)
            __builtin_amdgcn_s_sleep(1);
        __threadfence();
    }
    __syncthreads();
}

// ============ K1: projection (smi, pro) + drug_gat copy; zero barrier slots ============
__global__ __launch_bounds__(256) void k_proj2(
    const float* __restrict__ smi_tf, const float* __restrict__ pro_tf,
    const float* __restrict__ drug_gat, const float* __restrict__ w_att,
    const float* __restrict__ b_att,
    float* __restrict__ smi_attss, float* __restrict__ pro_att, int* __restrict__ bar)
{
    int blk = blockIdx.x, t = threadIdx.x;
    if (blk == 0 && t < 16) bar[t] = 0;
    int b = blk / PROJ_BPB;
    int r0 = (blk - b * PROJ_BPB) * PROJ_RPB;

    __shared__ float4 wl[64 * 17];   // [k][16 d4-slots + pad]
    __shared__ float4 rl4[16 * 17];  // [row][16 + pad]

    #pragma unroll
    for (int i2 = 0; i2 < 4; ++i2) {
        int f = t + 256 * i2;              // float4 index into w_att (1024 total)
        float4 v = ((const float4*)w_att)[f];
        wl[(f >> 4) * 17 + (f & 15)] = v;
    }
    int rl = t >> 4, p = t & 15;
    int r = r0 + rl;
    {
        float4 v = f4z();
        if (r < NROW) {
            const float* src;
            if (r < NSMI)      src = smi_tf   + (size_t)(b * NSMI + r) * D;
            else if (r < ND)   src = drug_gat + (size_t)(b * NATOM + (r - NSMI)) * D;
            else               src = pro_tf   + (size_t)(b * NP + (r - ND)) * D;
            v = ((const float4*)src)[p];
        }
        rl4[rl * 17 + p] = v;
    }
    __syncthreads();
    if (r >= NROW) return;
    float4 out;
    if (r >= NSMI && r < ND) {
        out = rl4[rl * 17 + p];            // drug_gat copy path
    } else {
        float4 acc = ((const float4*)b_att)[p];
        const float* rowf = (const float*)rl4;
        #pragma unroll
        for (int k = 0; k < 64; ++k) {
            float val = rowf[rl * 68 + k];
            float4 w = wl[k * 17 + p];
            acc.x = fmaf(val, w.x, acc.x);
            acc.y = fmaf(val, w.y, acc.y);
            acc.z = fmaf(val, w.z, acc.z);
            acc.w = fmaf(val, w.w, acc.w);
        }
        out = acc;
    }
    if (r < ND) ((float4*)smi_attss)[(size_t)(b * ND + r) * 16 + p] = out;
    else        ((float4*)pro_att)[(size_t)(b * NP + (r - ND)) * 16 + p] = out;
}

// ============ K2: fused pair-sums + gates, role-split blocks (unchanged) ============
__global__ __launch_bounds__(512) void k_pair(
    const float4* __restrict__ smi4, const float4* __restrict__ pro4,
    const float* __restrict__ smi_attss, const float* __restrict__ pro_tf,
    const float* __restrict__ w_att, const float* __restrict__ b_att,
    float* __restrict__ smi_tfs, float* __restrict__ pro_tfs)
{
    __shared__ float4 red[8][4][16];
    __shared__ float vl[4][64];
    int blk = blockIdx.x, t = threadIdx.x;
    int w = t >> 6, lane = t & 63, l = lane & 15, g = lane >> 4;
    int u = w * 4 + g;                       // 0..31
    float4 acc0 = f4z(), acc1 = f4z(), acc2 = f4z(), acc3 = f4z();
    int b, base;
    bool isRow = (blk < PAIR_ROW_BLKS);

    if (isRow) {
        b = blk / ROW_BPB;
        base = (blk - b * ROW_BPB) * 4;      // i0
        float4 a0 = (base + 0 < ND) ? smi4[(size_t)(b * ND + base + 0) * 16 + l] : f4z();
        float4 a1 = (base + 1 < ND) ? smi4[(size_t)(b * ND + base + 1) * 16 + l] : f4z();
        float4 a2 = (base + 2 < ND) ? smi4[(size_t)(b * ND + base + 2) * 16 + l] : f4z();
        float4 a3 = (base + 3 < ND) ? smi4[(size_t)(b * ND + base + 3) * 16 + l] : f4z();
        const float4* pp = pro4 + (size_t)b * NP * 16 + u * 16 + l;   // j = u + 32*it
        #pragma unroll 4
        for (int it = 0; it < 31; ++it) {
            float4 pv = pp[it * 512];
            acc_relu(acc0, a0, pv); acc_relu(acc1, a1, pv);
            acc_relu(acc2, a2, pv); acc_relu(acc3, a3, pv);
        }
        if (u < 8) {                          // j = u + 992 < 1000
            float4 pv = pp[31 * 512];
            acc_relu(acc0, a0, pv); acc_relu(acc1, a1, pv);
            acc_relu(acc2, a2, pv); acc_relu(acc3, a3, pv);
        }
    } else {
        int cb = blk - PAIR_ROW_BLKS;
        b = cb / COL_BPB;
        base = (cb - b * COL_BPB) * 4;       // j0
        float4 p0 = pro4[(size_t)(b * NP + base + 0) * 16 + l];
        float4 p1 = pro4[(size_t)(b * NP + base + 1) * 16 + l];
        float4 p2 = pro4[(size_t)(b * NP + base + 2) * 16 + l];
        float4 p3 = pro4[(size_t)(b * NP + base + 3) * 16 + l];
        const float4* ap = smi4 + (size_t)b * ND * 16 + u * 16 + l;   // i = u + 32*it
        #pragma unroll
        for (int it = 0; it < 4; ++it) {
            float4 av = ap[it * 512];
            acc_relu(acc0, av, p0); acc_relu(acc1, av, p1);
            acc_relu(acc2, av, p2); acc_relu(acc3, av, p3);
        }
        if (u < 17) {                         // i = u + 128 < 145
            float4 av = ap[4 * 512];
            acc_relu(acc0, av, p0); acc_relu(acc1, av, p1);
            acc_relu(acc2, av, p2); acc_relu(acc3, av, p3);
        }
    }

    wave_red_g(acc0); wave_red_g(acc1); wave_red_g(acc2); wave_red_g(acc3);
    if (lane < 16) {
        red[w][0][l] = acc0; red[w][1][l] = acc1;
        red[w][2][l] = acc2; red[w][3][l] = acc3;
    }
    __syncthreads();
    float invn = isRow ? (1.0f / NP) : (1.0f / ND);
    if (t < 64) {
        int ii = t >> 4, l2 = t & 15;
        float4 s = f4z();
        #pragma unroll
        for (int w2 = 0; w2 < 8; ++w2) f4acc(s, red[w2][ii][l2]);
        vl[ii][l2 * 4 + 0] = s.x * invn;
        vl[ii][l2 * 4 + 1] = s.y * invn;
        vl[ii][l2 * 4 + 2] = s.z * invn;
        vl[ii][l2 * 4 + 3] = s.w * invn;
    }
    __syncthreads();
    if (t < 256) {
        int ii = t >> 6, d = t & 63;
        int r = base + ii;
        bool ok = isRow ? (r < ND) : true;
        if (ok) {
            float m = b_att[d];
            #pragma unroll
            for (int k = 0; k < 64; ++k) m = fmaf(vl[ii][k], w_att[k * 64 + d], m);
            float gs = 1.f / (1.f + expf(-m));
            if (isRow) {
                size_t idx = (size_t)(b * ND + r) * 64 + d;
                smi_tfs[idx] = smi_attss[idx] * (0.5f + gs);
            } else {
                size_t idx = (size_t)(b * NP + r) * 64 + d;
                pro_tfs[idx] = pro_tf[idx] * (0.5f + gs);
            }
        }
    }
}

// ============ K3: pool + 4-layer MLP, 256 blocks x 512 threads, wide k-split ============
__global__ __launch_bounds__(512) void k_tail(
    const float4* __restrict__ smi_tfs4, const float4* __restrict__ pro_tfs4,
    const float* __restrict__ w1, const float* __restrict__ b1,
    const float* __restrict__ w2, const float* __restrict__ b2,
    const float* __restrict__ w3, const float* __restrict__ b3,
    const float* __restrict__ w4p, const float* __restrict__ b4p,
    float* __restrict__ x, float* __restrict__ h1, float* __restrict__ h2,
    float* __restrict__ h3, int* __restrict__ bar, float* __restrict__ out)
{
    __shared__ float4 ldsb[1024];            // 16 KB, reused per phase
    float* lds = (float*)ldsb;
    int blk = blockIdx.x, t = threadIdx.x;

    // ---- P0: mean pools -> x[B][128].  blocks 0..127: (b, s) d4-slice; rest idle
    if (blk < 128) {
        int b = blk >> 4, s = blk & 15;
        float4 sa = f4z(), pa = f4z();
        if (t < ND) f4acc(sa, smi_tfs4[(size_t)(b * ND + t) * 16 + s]);
        for (int j = t; j < NP; j += 512) f4acc(pa, pro_tfs4[(size_t)(b * NP + j) * 16 + s]);
        ldsb[t] = sa; ldsb[512 + t] = pa;
        __syncthreads();
        for (int st = 256; st > 0; st >>= 1) {
            if (t < st) { f4acc(ldsb[t], ldsb[t + st]); f4acc(ldsb[512 + t], ldsb[512 + t + st]); }
            __syncthreads();
        }
        if (t == 0) {
            float4 S = ldsb[0], P = ldsb[512];
            x[b * 128 + s * 4 + 0] = S.x * (1.0f / ND);
            x[b * 128 + s * 4 + 1] = S.y * (1.0f / ND);
            x[b * 128 + s * 4 + 2] = S.z * (1.0f / ND);
            x[b * 128 + s * 4 + 3] = S.w * (1.0f / ND);
            x[b * 128 + 64 + s * 4 + 0] = P.x * (1.0f / NP);
            x[b * 128 + 64 + s * 4 + 1] = P.y * (1.0f / NP);
            x[b * 128 + 64 + s * 4 + 2] = P.z * (1.0f / NP);
            x[b * 128 + 64 + s * 4 + 3] = P.w * (1.0f / NP);
        }
    }
    gridbar(bar, 0, TAIL_BLKS);

    // ---- P1: h1 = relu(x @ w1 + b1).  block (b, och32): 32 outputs, 16 kc x k-range 8
    {
        int b = blk >> 5, och = blk & 31;
        int ol = t & 31, kc = t >> 5;               // kc 0..15
        if (t < 128) lds[t] = x[b * 128 + t];
        __syncthreads();
        float acc = 0.f;
        const float* wp = w1 + (size_t)(kc * 8) * 1024 + och * 32 + ol;
        const float* xp = lds + kc * 8;
        #pragma unroll
        for (int k = 0; k < 8; ++k) acc = fmaf(xp[k], wp[(size_t)k * 1024], acc);
        lds[128 + t] = acc;
        __syncthreads();
        if (t < 32) {
            float v = b1[och * 32 + t];
            #pragma unroll
            for (int c = 0; c < 16; ++c) v += lds[128 + c * 32 + t];
            h1[b * 1024 + och * 32 + t] = fmaxf(v, 0.f);
        }
    }
    gridbar(bar, 1, TAIL_BLKS);

    // ---- P2: h2 = relu(h1 @ w2 + b2).  block (b, och32): 32 outputs, 16 kc x k-range 64
    {
        int b = blk >> 5, och = blk & 31;
        int ol = t & 31, kc = t >> 5;               // kc 0..15
        lds[t] = h1[b * 1024 + t];
        lds[512 + t] = h1[b * 1024 + 512 + t];
        __syncthreads();
        float acc = 0.f;
        const float* wp = w2 + (size_t)(kc * 64) * 1024 + och * 32 + ol;
        const float* hp = lds + kc * 64;
        #pragma unroll 8
        for (int k = 0; k < 64; ++k) acc = fmaf(hp[k], wp[(size_t)k * 1024], acc);
        lds[1024 + t] = acc;
        __syncthreads();
        if (t < 32) {
            float v = b2[och * 32 + t];
            #pragma unroll
            for (int c = 0; c < 16; ++c) v += lds[1024 + c * 32 + t];
            h2[b * 1024 + och * 32 + t] = fmaxf(v, 0.f);
        }
    }
    gridbar(bar, 2, TAIL_BLKS);

    // ---- P3: h3 = relu(h2 @ w3 + b3).  block (b, och32): 16 outputs, 32 kc x k-range 32
    {
        int b = blk >> 5, och = blk & 31;
        int ol = t & 15, kc = t >> 4;               // kc 0..31
        lds[t] = h2[b * 1024 + t];
        lds[512 + t] = h2[b * 1024 + 512 + t];
        __syncthreads();
        float acc = 0.f;
        const float* wp = w3 + (size_t)(kc * 32) * 512 + och * 16 + ol;
        const float* hp = lds + kc * 32;
        #pragma unroll 8
        for (int k = 0; k < 32; ++k) acc = fmaf(hp[k], wp[(size_t)k * 512], acc);
        lds[1024 + t] = acc;
        __syncthreads();
        if (t < 16) {
            float v = b3[och * 16 + t];
            #pragma unroll
            for (int c = 0; c < 32; ++c) v += lds[1024 + c * 16 + t];
            h3[b * 512 + och * 16 + t] = fmaxf(v, 0.f);
        }
    }
    gridbar(bar, 3, TAIL_BLKS);

    // ---- P4: out = h3 @ w4 + b4.  blocks 0..15: one (b,o) dot each
    if (blk < 16) {
        int b = blk >> 1, o = blk & 1;
        float acc = h3[b * 512 + t] * w4p[t * 2 + o];   // t < 512
        lds[t] = acc;
        __syncthreads();
        for (int st = 256; st > 0; st >>= 1) {
            if (t < st) lds[t] += lds[t + st];
            __syncthreads();
        }
        if (t == 0) out[b * 2 + o] = lds[0] + b4p[o];
    }
}

extern "C" void kernel_launch(void* const* d_in, const int* in_sizes, int n_in,
                              void* d_out, int out_size, void* d_ws, size_t ws_size,
                              hipStream_t stream)
{
    const float* smi_tf   = (const float*)d_in[0];
    const float* pro_tf   = (const float*)d_in[1];
    const float* drug_gat = (const float*)d_in[2];
    const float* w_att    = (const float*)d_in[3];
    const float* b_att    = (const float*)d_in[4];
    const float* w1 = (const float*)d_in[5];
    const float* b1 = (const float*)d_in[6];
    const float* w2 = (const float*)d_in[7];
    const float* b2 = (const float*)d_in[8];
    const float* w3 = (const float*)d_in[9];
    const float* b3 = (const float*)d_in[10];
    const float* w4 = (const float*)d_in[11];
    const float* b4 = (const float*)d_in[12];
    float* out = (float*)d_out;

    float* ws = (float*)d_ws;
    float* smi_attss = ws;                   // 74240
    float* pro_att   = smi_attss + 74240;    // 512000
    float* smi_tfs   = pro_att + 512000;     // 74240
    float* pro_tfs   = smi_tfs + 74240;      // 512000
    float* x   = pro_tfs + 512000;           // 1024
    float* h1  = x + 1024;                   // 8192
    float* h2  = h1 + 8192;                  // 8192
    float* h3  = h2 + 8192;                  // 4096
    int*   bar = (int*)(h3 + 4096);          // 16 ints

    k_proj2<<<B * PROJ_BPB, 256, 0, stream>>>(smi_tf, pro_tf, drug_gat, w_att, b_att,
                                              smi_attss, pro_att, bar);
    k_pair <<<PAIR_BLKS, 512, 0, stream>>>((const float4*)smi_attss, (const float4*)pro_att,
                                           smi_attss, pro_tf, w_att, b_att, smi_tfs, pro_tfs);
    k_tail <<<TAIL_BLKS, 512, 0, stream>>>((const float4*)smi_tfs, (const float4*)pro_tfs,
                                           w1, b1, w2, b2, w3, b3, w4, b4,
                                           x, h1, h2, h3, bar, out);
}

// Round 9
// 181.924 us; speedup vs baseline: 1.1631x; 1.1631x over previous
//
#include <hip/hip_runtime.h>
#include <math.h>

#define B 8
#define NSMI 100
#define NATOM 45
#define ND 145      // NSMI + NATOM
#define NP 1000
#define D 64
#define NROW 1145   // ND + NP rows per batch

#define PROJ_RPB 16
#define PROJ_BPB 72          // ceil(1145/16)
#define ROW_BPB 37           // ceil(145/4)   rowsum blocks per batch (4 i's each)
#define COL_BPB 250          // 1000/4        colsum blocks per batch (4 j's each)
#define PAIR_ROW_BLKS (B * ROW_BPB)            // 296
#define PAIR_BLKS (PAIR_ROW_BLKS + B * COL_BPB) // 2296
#define TAIL_BLKS 128        // proven barrier config (R7)

__device__ __forceinline__ float4 f4z() { float4 z; z.x = z.y = z.z = z.w = 0.f; return z; }
__device__ __forceinline__ void f4acc(float4& a, const float4& v) {
    a.x += v.x; a.y += v.y; a.z += v.z; a.w += v.w;
}
__device__ __forceinline__ void acc_relu(float4& acc, const float4& a, const float4& p) {
    acc.x += fmaxf(0.f, a.x + p.x);
    acc.y += fmaxf(0.f, a.y + p.y);
    acc.z += fmaxf(0.f, a.z + p.z);
    acc.w += fmaxf(0.f, a.w + p.w);
}
__device__ __forceinline__ void wave_red_g(float4& v) {
    v.x += __shfl_xor(v.x, 16, 64); v.x += __shfl_xor(v.x, 32, 64);
    v.y += __shfl_xor(v.y, 16, 64); v.y += __shfl_xor(v.y, 32, 64);
    v.z += __shfl_xor(v.z, 16, 64); v.z += __shfl_xor(v.z, 32, 64);
    v.w += __shfl_xor(v.w, 16, 64); v.w += __shfl_xor(v.w, 32, 64);
}

// device-scope grid barrier (TAIL_BLKS blocks co-resident)
__device__ __forceinline__ void gridbar(int* bar, int ph, int nblk) {
    __syncthreads();
    if (threadIdx.x == 0) {
        __threadfence();
        __hip_atomic_fetch_add(&bar[ph], 1, __ATOMIC_ACQ_REL, __HIP_MEMORY_SCOPE_AGENT);
        while (__hip_atomic_load(&bar[ph], __ATOMIC_ACQUIRE, __HIP_MEMORY_SCOPE_AGENT) < nblk)
            __builtin_amdgcn_s_sleep(1);
        __threadfence();
    }
    __syncthreads();
}

// ============ K1: projection (smi, pro) + drug_gat copy; zero barrier slots ============
__global__ __launch_bounds__(256) void k_proj2(
    const float* __restrict__ smi_tf, const float* __restrict__ pro_tf,
    const float* __restrict__ drug_gat, const float* __restrict__ w_att,
    const float* __restrict__ b_att,
    float* __restrict__ smi_attss, float* __restrict__ pro_att, int* __restrict__ bar)
{
    int blk = blockIdx.x, t = threadIdx.x;
    if (blk == 0 && t < 16) bar[t] = 0;
    int b = blk / PROJ_BPB;
    int r0 = (blk - b * PROJ_BPB) * PROJ_RPB;

    __shared__ float4 wl[64 * 17];   // [k][16 d4-slots + pad]
    __shared__ float4 rl4[16 * 17];  // [row][16 + pad]

    #pragma unroll
    for (int i2 = 0; i2 < 4; ++i2) {
        int f = t + 256 * i2;              // float4 index into w_att (1024 total)
        float4 v = ((const float4*)w_att)[f];
        wl[(f >> 4) * 17 + (f & 15)] = v;
    }
    int rl = t >> 4, p = t & 15;
    int r = r0 + rl;
    {
        float4 v = f4z();
        if (r < NROW) {
            const float* src;
            if (r < NSMI)      src = smi_tf   + (size_t)(b * NSMI + r) * D;
            else if (r < ND)   src = drug_gat + (size_t)(b * NATOM + (r - NSMI)) * D;
            else               src = pro_tf   + (size_t)(b * NP + (r - ND)) * D;
            v = ((const float4*)src)[p];
        }
        rl4[rl * 17 + p] = v;
    }
    __syncthreads();
    if (r >= NROW) return;
    float4 out;
    if (r >= NSMI && r < ND) {
        out = rl4[rl * 17 + p];            // drug_gat copy path
    } else {
        float4 acc = ((const float4*)b_att)[p];
        const float* rowf = (const float*)rl4;
        #pragma unroll
        for (int k = 0; k < 64; ++k) {
            float val = rowf[rl * 68 + k];
            float4 w = wl[k * 17 + p];
            acc.x = fmaf(val, w.x, acc.x);
            acc.y = fmaf(val, w.y, acc.y);
            acc.z = fmaf(val, w.z, acc.z);
            acc.w = fmaf(val, w.w, acc.w);
        }
        out = acc;
    }
    if (r < ND) ((float4*)smi_attss)[(size_t)(b * ND + r) * 16 + p] = out;
    else        ((float4*)pro_att)[(size_t)(b * NP + (r - ND)) * 16 + p] = out;
}

// ============ K2: fused pair-sums + gates, role-split blocks (unchanged) ============
__global__ __launch_bounds__(512) void k_pair(
    const float4* __restrict__ smi4, const float4* __restrict__ pro4,
    const float* __restrict__ smi_attss, const float* __restrict__ pro_tf,
    const float* __restrict__ w_att, const float* __restrict__ b_att,
    float* __restrict__ smi_tfs, float* __restrict__ pro_tfs)
{
    __shared__ float4 red[8][4][16];
    __shared__ float vl[4][64];
    int blk = blockIdx.x, t = threadIdx.x;
    int w = t >> 6, lane = t & 63, l = lane & 15, g = lane >> 4;
    int u = w * 4 + g;                       // 0..31
    float4 acc0 = f4z(), acc1 = f4z(), acc2 = f4z(), acc3 = f4z();
    int b, base;
    bool isRow = (blk < PAIR_ROW_BLKS);

    if (isRow) {
        b = blk / ROW_BPB;
        base = (blk - b * ROW_BPB) * 4;      // i0
        float4 a0 = (base + 0 < ND) ? smi4[(size_t)(b * ND + base + 0) * 16 + l] : f4z();
        float4 a1 = (base + 1 < ND) ? smi4[(size_t)(b * ND + base + 1) * 16 + l] : f4z();
        float4 a2 = (base + 2 < ND) ? smi4[(size_t)(b * ND + base + 2) * 16 + l] : f4z();
        float4 a3 = (base + 3 < ND) ? smi4[(size_t)(b * ND + base + 3) * 16 + l] : f4z();
        const float4* pp = pro4 + (size_t)b * NP * 16 + u * 16 + l;   // j = u + 32*it
        #pragma unroll 4
        for (int it = 0; it < 31; ++it) {
            float4 pv = pp[it * 512];
            acc_relu(acc0, a0, pv); acc_relu(acc1, a1, pv);
            acc_relu(acc2, a2, pv); acc_relu(acc3, a3, pv);
        }
        if (u < 8) {                          // j = u + 992 < 1000
            float4 pv = pp[31 * 512];
            acc_relu(acc0, a0, pv); acc_relu(acc1, a1, pv);
            acc_relu(acc2, a2, pv); acc_relu(acc3, a3, pv);
        }
    } else {
        int cb = blk - PAIR_ROW_BLKS;
        b = cb / COL_BPB;
        base = (cb - b * COL_BPB) * 4;       // j0
        float4 p0 = pro4[(size_t)(b * NP + base + 0) * 16 + l];
        float4 p1 = pro4[(size_t)(b * NP + base + 1) * 16 + l];
        float4 p2 = pro4[(size_t)(b * NP + base + 2) * 16 + l];
        float4 p3 = pro4[(size_t)(b * NP + base + 3) * 16 + l];
        const float4* ap = smi4 + (size_t)b * ND * 16 + u * 16 + l;   // i = u + 32*it
        #pragma unroll
        for (int it = 0; it < 4; ++it) {
            float4 av = ap[it * 512];
            acc_relu(acc0, av, p0); acc_relu(acc1, av, p1);
            acc_relu(acc2, av, p2); acc_relu(acc3, av, p3);
        }
        if (u < 17) {                         // i = u + 128 < 145
            float4 av = ap[4 * 512];
            acc_relu(acc0, av, p0); acc_relu(acc1, av, p1);
            acc_relu(acc2, av, p2); acc_relu(acc3, av, p3);
        }
    }

    wave_red_g(acc0); wave_red_g(acc1); wave_red_g(acc2); wave_red_g(acc3);
    if (lane < 16) {
        red[w][0][l] = acc0; red[w][1][l] = acc1;
        red[w][2][l] = acc2; red[w][3][l] = acc3;
    }
    __syncthreads();
    float invn = isRow ? (1.0f / NP) : (1.0f / ND);
    if (t < 64) {
        int ii = t >> 4, l2 = t & 15;
        float4 s = f4z();
        #pragma unroll
        for (int w2 = 0; w2 < 8; ++w2) f4acc(s, red[w2][ii][l2]);
        vl[ii][l2 * 4 + 0] = s.x * invn;
        vl[ii][l2 * 4 + 1] = s.y * invn;
        vl[ii][l2 * 4 + 2] = s.z * invn;
        vl[ii][l2 * 4 + 3] = s.w * invn;
    }
    __syncthreads();
    if (t < 256) {
        int ii = t >> 6, d = t & 63;
        int r = base + ii;
        bool ok = isRow ? (r < ND) : true;
        if (ok) {
            float m = b_att[d];
            #pragma unroll
            for (int k = 0; k < 64; ++k) m = fmaf(vl[ii][k], w_att[k * 64 + d], m);
            float gs = 1.f / (1.f + expf(-m));
            if (isRow) {
                size_t idx = (size_t)(b * ND + r) * 64 + d;
                smi_tfs[idx] = smi_attss[idx] * (0.5f + gs);
            } else {
                size_t idx = (size_t)(b * NP + r) * 64 + d;
                pro_tfs[idx] = pro_tf[idx] * (0.5f + gs);
            }
        }
    }
}

// ============ K3: pool + MLP, row-streamed weights, batch-shared loads ============
// 128 blocks x 512 threads. Partials per layer; reduce folded into next phase's staging.
// part1[32][8][1024], part2[64][8][1024], part3[64][8][512]
__global__ __launch_bounds__(512) void k_tail(
    const float4* __restrict__ smi_tfs4, const float4* __restrict__ pro_tfs4,
    const float4* __restrict__ w1_4, const float* __restrict__ b1,
    const float4* __restrict__ w2_4, const float* __restrict__ b2,
    const float4* __restrict__ w3_4, const float* __restrict__ b3,
    const float* __restrict__ w4p, const float* __restrict__ b4p,
    float* __restrict__ x, float* __restrict__ part1, float* __restrict__ part2,
    float* __restrict__ part3, int* __restrict__ bar, float* __restrict__ out)
{
    __shared__ float4 ldsb[1024];            // 16 KB, reused per phase
    float* lds = (float*)ldsb;
    int blk = blockIdx.x, t = threadIdx.x;

    // ---- P0: mean pools -> x[B][128].  blocks (b, s): d4-slice s of batch b
    {
        int b = blk >> 4, s = blk & 15;
        float4 sa = f4z(), pa = f4z();
        if (t < ND) f4acc(sa, smi_tfs4[(size_t)(b * ND + t) * 16 + s]);
        for (int j = t; j < NP; j += 512) f4acc(pa, pro_tfs4[(size_t)(b * NP + j) * 16 + s]);
        ldsb[t] = sa; ldsb[512 + t] = pa;
        __syncthreads();
        for (int st = 256; st > 0; st >>= 1) {
            if (t < st) { f4acc(ldsb[t], ldsb[t + st]); f4acc(ldsb[512 + t], ldsb[512 + t + st]); }
            __syncthreads();
        }
        if (t == 0) {
            float4 S = ldsb[0], P = ldsb[512];
            x[b * 128 + s * 4 + 0] = S.x * (1.0f / ND);
            x[b * 128 + s * 4 + 1] = S.y * (1.0f / ND);
            x[b * 128 + s * 4 + 2] = S.z * (1.0f / ND);
            x[b * 128 + s * 4 + 3] = S.w * (1.0f / ND);
            x[b * 128 + 64 + s * 4 + 0] = P.x * (1.0f / NP);
            x[b * 128 + 64 + s * 4 + 1] = P.y * (1.0f / NP);
            x[b * 128 + 64 + s * 4 + 2] = P.z * (1.0f / NP);
            x[b * 128 + 64 + s * 4 + 3] = P.w * (1.0f / NP);
        }
    }
    gridbar(bar, 0, TAIL_BLKS);

    // ---- P1: part1[vc][b][:] = x[b, vc*4:+4] @ w1[vc*4:+4, :]   (32 blocks, k-range 4)
    if (blk < 32) {
        int vc = blk;
        if (t < 32) {                         // xs[b*4+kk]
            int b = t >> 2, kk = t & 3;
            lds[t] = x[b * 128 + vc * 4 + kk];
        }
        __syncthreads();
        if (t < 256) {
            int o4 = t;
            float4 acc[8];
            #pragma unroll
            for (int b = 0; b < 8; ++b) acc[b] = f4z();
            #pragma unroll
            for (int kk = 0; kk < 4; ++kk) {
                float4 wv = w1_4[(size_t)(vc * 4 + kk) * 256 + o4];
                #pragma unroll
                for (int b = 0; b < 8; ++b) {
                    float xv = lds[b * 4 + kk];
                    acc[b].x = fmaf(xv, wv.x, acc[b].x);
                    acc[b].y = fmaf(xv, wv.y, acc[b].y);
                    acc[b].z = fmaf(xv, wv.z, acc[b].z);
                    acc[b].w = fmaf(xv, wv.w, acc[b].w);
                }
            }
            #pragma unroll
            for (int b = 0; b < 8; ++b)
                ((float4*)part1)[(size_t)(vc * 8 + b) * 256 + o4] = acc[b];
        }
    }
    gridbar(bar, 1, TAIL_BLKS);

    // ---- P2: h1-slice = relu(b1 + sum_p part1) staged; part2[vc][b][:] (64 blocks, k-range 16)
    if (blk < 64) {
        int vc = blk, kbase = vc * 16;
        if (t < 256) {                        // psum: pair=(b,kk), half over p
            int pair = t & 127, half = t >> 7;
            int b = pair >> 4, kk = pair & 15;
            const float* pp = part1 + (size_t)(half * 16 * 8 + b) * 1024 + kbase + kk;
            float s = 0.f;
            #pragma unroll
            for (int p = 0; p < 16; ++p) s += pp[(size_t)p * 8192];
            lds[t] = s;
        }
        __syncthreads();
        if (t < 128) {
            int b = t >> 4, kk = t & 15;
            float s = lds[t] + lds[t + 128];
            lds[256 + t] = fmaxf(0.f, b1[kbase + kk] + s);   // h1s[b*16+kk]
        }
        __syncthreads();
        if (t < 256) {
            int o4 = t;
            float4 acc[8];
            #pragma unroll
            for (int b = 0; b < 8; ++b) acc[b] = f4z();
            #pragma unroll
            for (int kk = 0; kk < 16; ++kk) {
                float4 wv = w2_4[(size_t)(kbase + kk) * 256 + o4];
                #pragma unroll
                for (int b = 0; b < 8; ++b) {
                    float hv = lds[256 + b * 16 + kk];
                    acc[b].x = fmaf(hv, wv.x, acc[b].x);
                    acc[b].y = fmaf(hv, wv.y, acc[b].y);
                    acc[b].z = fmaf(hv, wv.z, acc[b].z);
                    acc[b].w = fmaf(hv, wv.w, acc[b].w);
                }
            }
            #pragma unroll
            for (int b = 0; b < 8; ++b)
                ((float4*)part2)[(size_t)(vc * 8 + b) * 256 + o4] = acc[b];
        }
    }
    gridbar(bar, 2, TAIL_BLKS);

    // ---- P3: h2-slice = relu(b2 + sum_p part2) staged; part3[slot][b][:] (32 blocks, k-range 32)
    if (blk < 32) {
        int vc = blk, kbase = vc * 32;
        if (t < 256) {                        // h2s[b*32+kk]
            int b = t >> 5, kk = t & 31;
            const float* pp = part2 + (size_t)b * 1024 + kbase + kk;
            float s = 0.f;
            #pragma unroll 8
            for (int p = 0; p < 64; ++p) s += pp[(size_t)p * 8192];
            lds[t] = fmaxf(0.f, b2[kbase + kk] + s);
        }
        __syncthreads();
        if (t < 256) {
            int o4 = t & 127, ksub = t >> 7;
            float4 acc[8];
            #pragma unroll
            for (int b = 0; b < 8; ++b) acc[b] = f4z();
            #pragma unroll
            for (int kk = 0; kk < 16; ++kk) {
                int k = kbase + ksub * 16 + kk;
                float4 wv = w3_4[(size_t)k * 128 + o4];
                #pragma unroll
                for (int b = 0; b < 8; ++b) {
                    float hv = lds[b * 32 + ksub * 16 + kk];
                    acc[b].x = fmaf(hv, wv.x, acc[b].x);
                    acc[b].y = fmaf(hv, wv.y, acc[b].y);
                    acc[b].z = fmaf(hv, wv.z, acc[b].z);
                    acc[b].w = fmaf(hv, wv.w, acc[b].w);
                }
            }
            #pragma unroll
            for (int b = 0; b < 8; ++b)
                ((float4*)part3)[(size_t)((vc * 2 + ksub) * 8 + b) * 128 + o4] = acc[b];
        }
    }
    gridbar(bar, 3, TAIL_BLKS);

    // ---- P4: per-b: h3 = relu(b3 + sum_p part3); out = h3 @ w4 + b4  (8 blocks)
    if (blk < 8) {
        int b = blk;
        int o = t;                            // 512 outputs, one per thread
        const float* pp = part3 + (size_t)b * 512 + o;
        float s = 0.f;
        #pragma unroll 8
        for (int p = 0; p < 64; ++p) s += pp[(size_t)p * 4096];
        float h = fmaxf(0.f, b3[o] + s);
        lds[t] = h * w4p[o * 2 + 0];
        lds[512 + t] = h * w4p[o * 2 + 1];
        __syncthreads();
        for (int st = 256; st > 0; st >>= 1) {
            if (t < st) { lds[t] += lds[t + st]; lds[512 + t] += lds[512 + t + st]; }
            __syncthreads();
        }
        if (t == 0) {
            out[b * 2 + 0] = lds[0] + b4p[0];
            out[b * 2 + 1] = lds[512] + b4p[1];
        }
    }
}

extern "C" void kernel_launch(void* const* d_in, const int* in_sizes, int n_in,
                              void* d_out, int out_size, void* d_ws, size_t ws_size,
                              hipStream_t stream)
{
    const float* smi_tf   = (const float*)d_in[0];
    const float* pro_tf   = (const float*)d_in[1];
    const float* drug_gat = (const float*)d_in[2];
    const float* w_att    = (const float*)d_in[3];
    const float* b_att    = (const float*)d_in[4];
    const float* w1 = (const float*)d_in[5];
    const float* b1 = (const float*)d_in[6];
    const float* w2 = (const float*)d_in[7];
    const float* b2 = (const float*)d_in[8];
    const float* w3 = (const float*)d_in[9];
    const float* b3 = (const float*)d_in[10];
    const float* w4 = (const float*)d_in[11];
    const float* b4 = (const float*)d_in[12];
    float* out = (float*)d_out;

    float* ws = (float*)d_ws;
    float* smi_attss = ws;                    // 74240
    float* pro_att   = smi_attss + 74240;     // 512000
    float* smi_tfs   = pro_att + 512000;      // 74240
    float* pro_tfs   = smi_tfs + 74240;       // 512000
    float* x     = pro_tfs + 512000;          // 1024
    float* part1 = x + 1024;                  // 32*8*1024 = 262144
    float* part2 = part1 + 262144;            // 64*8*1024 = 524288
    float* part3 = part2 + 524288;            // 64*8*512  = 262144
    int*   bar  = (int*)(part3 + 262144);     // 16 ints

    k_proj2<<<B * PROJ_BPB, 256, 0, stream>>>(smi_tf, pro_tf, drug_gat, w_att, b_att,
                                              smi_attss, pro_att, bar);
    k_pair <<<PAIR_BLKS, 512, 0, stream>>>((const float4*)smi_attss, (const float4*)pro_att,
                                           smi_attss, pro_tf, w_att, b_att, smi_tfs, pro_tfs);
    k_tail <<<TAIL_BLKS, 512, 0, stream>>>((const float4*)smi_tfs, (const float4*)pro_tfs,
                                           (const float4*)w1, b1, (const float4*)w2, b2,
                                           (const float4*)w3, b3, w4, b4,
                                           x, part1, part2, part3, bar, out);
}

// Round 12
// 129.838 us; speedup vs baseline: 1.6297x; 1.4012x over previous
//
#include <hip/hip_runtime.h>
#include <math.h>

#define B 8
#define NSMI 100
#define NATOM 45
#define ND 145      // NSMI + NATOM
#define NP 1000
#define D 64
#define NROW 1145   // ND + NP rows per batch

#define PROJ_RPB 16
#define PROJ_BPB 72          // ceil(1145/16)
#define ROW_BPB 37           // ceil(145/4)
#define COL_BPB 250          // 1000/4
#define PAIR_ROW_BLKS (B * ROW_BPB)            // 296
#define PAIR_BLKS (PAIR_ROW_BLKS + B * COL_BPB) // 2296

__device__ __forceinline__ float4 f4z() { float4 z; z.x = z.y = z.z = z.w = 0.f; return z; }
__device__ __forceinline__ void f4acc(float4& a, const float4& v) {
    a.x += v.x; a.y += v.y; a.z += v.z; a.w += v.w;
}
__device__ __forceinline__ void acc_relu(float4& acc, const float4& a, const float4& p) {
    acc.x += fmaxf(0.f, a.x + p.x);
    acc.y += fmaxf(0.f, a.y + p.y);
    acc.z += fmaxf(0.f, a.z + p.z);
    acc.w += fmaxf(0.f, a.w + p.w);
}
__device__ __forceinline__ void wave_red_g(float4& v) {
    v.x += __shfl_xor(v.x, 16, 64); v.x += __shfl_xor(v.x, 32, 64);
    v.y += __shfl_xor(v.y, 16, 64); v.y += __shfl_xor(v.y, 32, 64);
    v.z += __shfl_xor(v.z, 16, 64); v.z += __shfl_xor(v.z, 32, 64);
    v.w += __shfl_xor(v.w, 16, 64); v.w += __shfl_xor(v.w, 32, 64);
}

// ============ K1: projection (smi, pro) + drug_gat copy ============
__global__ __launch_bounds__(256) void k_proj2(
    const float* __restrict__ smi_tf, const float* __restrict__ pro_tf,
    const float* __restrict__ drug_gat, const float* __restrict__ w_att,
    const float* __restrict__ b_att,
    float* __restrict__ smi_attss, float* __restrict__ pro_att)
{
    int blk = blockIdx.x, t = threadIdx.x;
    int b = blk / PROJ_BPB;
    int r0 = (blk - b * PROJ_BPB) * PROJ_RPB;

    __shared__ float4 wl[64 * 17];
    __shared__ float4 rl4[16 * 17];

    #pragma unroll
    for (int i2 = 0; i2 < 4; ++i2) {
        int f = t + 256 * i2;
        float4 v = ((const float4*)w_att)[f];
        wl[(f >> 4) * 17 + (f & 15)] = v;
    }
    int rl = t >> 4, p = t & 15;
    int r = r0 + rl;
    {
        float4 v = f4z();
        if (r < NROW) {
            const float* src;
            if (r < NSMI)      src = smi_tf   + (size_t)(b * NSMI + r) * D;
            else if (r < ND)   src = drug_gat + (size_t)(b * NATOM + (r - NSMI)) * D;
            else               src = pro_tf   + (size_t)(b * NP + (r - ND)) * D;
            v = ((const float4*)src)[p];
        }
        rl4[rl * 17 + p] = v;
    }
    __syncthreads();
    if (r >= NROW) return;
    float4 out;
    if (r >= NSMI && r < ND) {
        out = rl4[rl * 17 + p];
    } else {
        float4 acc = ((const float4*)b_att)[p];
        const float* rowf = (const float*)rl4;
        #pragma unroll
        for (int k = 0; k < 64; ++k) {
            float val = rowf[rl * 68 + k];
            float4 w = wl[k * 17 + p];
            acc.x = fmaf(val, w.x, acc.x);
            acc.y = fmaf(val, w.y, acc.y);
            acc.z = fmaf(val, w.z, acc.z);
            acc.w = fmaf(val, w.w, acc.w);
        }
        out = acc;
    }
    if (r < ND) ((float4*)smi_attss)[(size_t)(b * ND + r) * 16 + p] = out;
    else        ((float4*)pro_att)[(size_t)(b * NP + (r - ND)) * 16 + p] = out;
}

// ============ K2: fused pair-sums + gates (unchanged) ============
__global__ __launch_bounds__(512) void k_pair(
    const float4* __restrict__ smi4, const float4* __restrict__ pro4,
    const float* __restrict__ smi_attss, const float* __restrict__ pro_tf,
    const float* __restrict__ w_att, const float* __restrict__ b_att,
    float* __restrict__ smi_tfs, float* __restrict__ pro_tfs)
{
    __shared__ float4 red[8][4][16];
    __shared__ float vl[4][64];
    int blk = blockIdx.x, t = threadIdx.x;
    int w = t >> 6, lane = t & 63, l = lane & 15, g = lane >> 4;
    int u = w * 4 + g;
    float4 acc0 = f4z(), acc1 = f4z(), acc2 = f4z(), acc3 = f4z();
    int b, base;
    bool isRow = (blk < PAIR_ROW_BLKS);

    if (isRow) {
        b = blk / ROW_BPB;
        base = (blk - b * ROW_BPB) * 4;
        float4 a0 = (base + 0 < ND) ? smi4[(size_t)(b * ND + base + 0) * 16 + l] : f4z();
        float4 a1 = (base + 1 < ND) ? smi4[(size_t)(b * ND + base + 1) * 16 + l] : f4z();
        float4 a2 = (base + 2 < ND) ? smi4[(size_t)(b * ND + base + 2) * 16 + l] : f4z();
        float4 a3 = (base + 3 < ND) ? smi4[(size_t)(b * ND + base + 3) * 16 + l] : f4z();
        const float4* pp = pro4 + (size_t)b * NP * 16 + u * 16 + l;
        #pragma unroll 4
        for (int it = 0; it < 31; ++it) {
            float4 pv = pp[it * 512];
            acc_relu(acc0, a0, pv); acc_relu(acc1, a1, pv);
            acc_relu(acc2, a2, pv); acc_relu(acc3, a3, pv);
        }
        if (u < 8) {
            float4 pv = pp[31 * 512];
            acc_relu(acc0, a0, pv); acc_relu(acc1, a1, pv);
            acc_relu(acc2, a2, pv); acc_relu(acc3, a3, pv);
        }
    } else {
        int cb = blk - PAIR_ROW_BLKS;
        b = cb / COL_BPB;
        base = (cb - b * COL_BPB) * 4;
        float4 p0 = pro4[(size_t)(b * NP + base + 0) * 16 + l];
        float4 p1 = pro4[(size_t)(b * NP + base + 1) * 16 + l];
        float4 p2 = pro4[(size_t)(b * NP + base + 2) * 16 + l];
        float4 p3 = pro4[(size_t)(b * NP + base + 3) * 16 + l];
        const float4* ap = smi4 + (size_t)b * ND * 16 + u * 16 + l;
        #pragma unroll
        for (int it = 0; it < 4; ++it) {
            float4 av = ap[it * 512];
            acc_relu(acc0, av, p0); acc_relu(acc1, av, p1);
            acc_relu(acc2, av, p2); acc_relu(acc3, av, p3);
        }
        if (u < 17) {
            float4 av = ap[4 * 512];
            acc_relu(acc0, av, p0); acc_relu(acc1, av, p1);
            acc_relu(acc2, av, p2); acc_relu(acc3, av, p3);
        }
    }

    wave_red_g(acc0); wave_red_g(acc1); wave_red_g(acc2); wave_red_g(acc3);
    if (lane < 16) {
        red[w][0][l] = acc0; red[w][1][l] = acc1;
        red[w][2][l] = acc2; red[w][3][l] = acc3;
    }
    __syncthreads();
    float invn = isRow ? (1.0f / NP) : (1.0f / ND);
    if (t < 64) {
        int ii = t >> 4, l2 = t & 15;
        float4 s = f4z();
        #pragma unroll
        for (int w2 = 0; w2 < 8; ++w2) f4acc(s, red[w2][ii][l2]);
        vl[ii][l2 * 4 + 0] = s.x * invn;
        vl[ii][l2 * 4 + 1] = s.y * invn;
        vl[ii][l2 * 4 + 2] = s.z * invn;
        vl[ii][l2 * 4 + 3] = s.w * invn;
    }
    __syncthreads();
    if (t < 256) {
        int ii = t >> 6, d = t & 63;
        int r = base + ii;
        bool ok = isRow ? (r < ND) : true;
        if (ok) {
            float m = b_att[d];
            #pragma unroll
            for (int k = 0; k < 64; ++k) m = fmaf(vl[ii][k], w_att[k * 64 + d], m);
            float gs = 1.f / (1.f + expf(-m));
            if (isRow) {
                size_t idx = (size_t)(b * ND + r) * 64 + d;
                smi_tfs[idx] = smi_attss[idx] * (0.5f + gs);
            } else {
                size_t idx = (size_t)(b * NP + r) * 64 + d;
                pro_tfs[idx] = pro_tf[idx] * (0.5f + gs);
            }
        }
    }
}

// ============ K3: mean pools -> x[B][128] (128 blocks x 512) ============
__global__ __launch_bounds__(512) void k_pool(
    const float4* __restrict__ smi_tfs4, const float4* __restrict__ pro_tfs4,
    float* __restrict__ x)
{
    __shared__ float4 ldsb[1024];
    int blk = blockIdx.x, t = threadIdx.x;
    int b = blk >> 4, s = blk & 15;
    float4 sa = f4z(), pa = f4z();
    if (t < ND) f4acc(sa, smi_tfs4[(size_t)(b * ND + t) * 16 + s]);
    for (int j = t; j < NP; j += 512) f4acc(pa, pro_tfs4[(size_t)(b * NP + j) * 16 + s]);
    ldsb[t] = sa; ldsb[512 + t] = pa;
    __syncthreads();
    for (int st = 256; st > 0; st >>= 1) {
        if (t < st) { f4acc(ldsb[t], ldsb[t + st]); f4acc(ldsb[512 + t], ldsb[512 + t + st]); }
        __syncthreads();
    }
    if (t == 0) {
        float4 S = ldsb[0], P = ldsb[512];
        x[b * 128 + s * 4 + 0] = S.x * (1.0f / ND);
        x[b * 128 + s * 4 + 1] = S.y * (1.0f / ND);
        x[b * 128 + s * 4 + 2] = S.z * (1.0f / ND);
        x[b * 128 + s * 4 + 3] = S.w * (1.0f / ND);
        x[b * 128 + 64 + s * 4 + 0] = P.x * (1.0f / NP);
        x[b * 128 + 64 + s * 4 + 1] = P.y * (1.0f / NP);
        x[b * 128 + 64 + s * 4 + 2] = P.z * (1.0f / NP);
        x[b * 128 + 64 + s * 4 + 3] = P.w * (1.0f / NP);
    }
}

// ============ L1: h1 = relu(x@w1+b1). 16 blocks x 256. Full in-block K-reduce ============
// block oc: o4 in [oc*16, oc*16+16). thread: ol=t&15, g=t>>4 (16 k-groups of 8)
__global__ __launch_bounds__(256) void k_l1(
    const float4* __restrict__ x4, const float4* __restrict__ w1_4,
    const float4* __restrict__ b1_4, float4* __restrict__ h1_4)
{
    __shared__ float lds_x[1024];
    __shared__ float4 red[2048];     // [g16][ol16][b8]
    int oc = blockIdx.x, t = threadIdx.x;
    ((float4*)lds_x)[t] = x4[t];     // 256 f4 = whole x
    __syncthreads();
    int ol = t & 15, g = t >> 4;
    int o4 = oc * 16 + ol;
    float4 acc[8];
    #pragma unroll
    for (int b = 0; b < 8; ++b) acc[b] = f4z();
    #pragma unroll
    for (int kk = 0; kk < 8; ++kk) {
        int k = g * 8 + kk;
        float4 wv = w1_4[(size_t)k * 256 + o4];
        #pragma unroll
        for (int b = 0; b < 8; ++b) {
            float xv = lds_x[b * 128 + k];
            acc[b].x = fmaf(xv, wv.x, acc[b].x);
            acc[b].y = fmaf(xv, wv.y, acc[b].y);
            acc[b].z = fmaf(xv, wv.z, acc[b].z);
            acc[b].w = fmaf(xv, wv.w, acc[b].w);
        }
    }
    #pragma unroll
    for (int b = 0; b < 8; ++b) red[g * 128 + ol * 8 + b] = acc[b];
    __syncthreads();
    int u = t & 127, gg = t >> 7;    // gg 0..1, sums 8 g's each
    float4 s = f4z();
    #pragma unroll
    for (int j = 0; j < 8; ++j) f4acc(s, red[(gg * 8 + j) * 128 + u]);
    red[gg * 8 * 128 + u] = s;
    __syncthreads();
    if (t < 128) {
        float4 v = red[t];
        f4acc(v, red[1024 + t]);
        int olr = t >> 3, b = t & 7;
        float4 bb = b1_4[oc * 16 + olr];
        v.x = fmaxf(v.x + bb.x, 0.f); v.y = fmaxf(v.y + bb.y, 0.f);
        v.z = fmaxf(v.z + bb.z, 0.f); v.w = fmaxf(v.w + bb.w, 0.f);
        h1_4[b * 256 + oc * 16 + olr] = v;
    }
}

// ============ L2: h2 = relu(h1@w2+b2). 64 blocks x 512. Full in-block K-reduce ============
// block oc: o4 in [oc*4,+4). thread: ol=t&3, g=t>>2 (128 k-groups of 8)
__global__ __launch_bounds__(512) void k_l2(
    const float4* __restrict__ h1_4, const float4* __restrict__ w2_4,
    const float4* __restrict__ b2_4, float4* __restrict__ h2_4)
{
    __shared__ float4 buf[4096];     // 64KB: stage (2048 f4) then red (4096 f4)
    float* lds_h = (float*)buf;
    int oc = blockIdx.x, t = threadIdx.x;
    #pragma unroll
    for (int j = 0; j < 4; ++j) buf[t + 512 * j] = h1_4[t + 512 * j];
    __syncthreads();
    int ol = t & 3, g = t >> 2;
    int o4 = oc * 4 + ol;
    float4 acc[8];
    #pragma unroll
    for (int b = 0; b < 8; ++b) acc[b] = f4z();
    #pragma unroll
    for (int kk = 0; kk < 8; ++kk) {
        int k = g * 8 + kk;
        float4 wv = w2_4[(size_t)k * 256 + o4];
        #pragma unroll
        for (int b = 0; b < 8; ++b) {
            float hv = lds_h[b * 1024 + k];
            acc[b].x = fmaf(hv, wv.x, acc[b].x);
            acc[b].y = fmaf(hv, wv.y, acc[b].y);
            acc[b].z = fmaf(hv, wv.z, acc[b].z);
            acc[b].w = fmaf(hv, wv.w, acc[b].w);
        }
    }
    __syncthreads();                 // stage no longer needed
    #pragma unroll
    for (int b = 0; b < 8; ++b) buf[g * 32 + ol * 8 + b] = acc[b];
    __syncthreads();
    int u = t & 31, gg = t >> 5;     // gg 0..15, sums 8 g's each
    float4 s = f4z();
    #pragma unroll
    for (int j = 0; j < 8; ++j) f4acc(s, buf[(gg * 8 + j) * 32 + u]);
    buf[gg * 256 + u] = s;
    __syncthreads();
    if (t < 32) {
        float4 v = f4z();
        #pragma unroll
        for (int gg2 = 0; gg2 < 16; ++gg2) f4acc(v, buf[gg2 * 256 + t]);
        int olr = t >> 3, b = t & 7;
        float4 bb = b2_4[oc * 4 + olr];
        v.x = fmaxf(v.x + bb.x, 0.f); v.y = fmaxf(v.y + bb.y, 0.f);
        v.z = fmaxf(v.z + bb.z, 0.f); v.w = fmaxf(v.w + bb.w, 0.f);
        h2_4[b * 256 + oc * 4 + olr] = v;
    }
}

// ============ L3: h3 = relu(h2@w3+b3). 32 blocks x 512. Same pattern, O=512 ============
__global__ __launch_bounds__(512) void k_l3(
    const float4* __restrict__ h2_4, const float4* __restrict__ w3_4,
    const float4* __restrict__ b3_4, float4* __restrict__ h3_4)
{
    __shared__ float4 buf[4096];
    float* lds_h = (float*)buf;
    int oc = blockIdx.x, t = threadIdx.x;
    #pragma unroll
    for (int j = 0; j < 4; ++j) buf[t + 512 * j] = h2_4[t + 512 * j];
    __syncthreads();
    int ol = t & 3, g = t >> 2;
    int o4 = oc * 4 + ol;            // < 128
    float4 acc[8];
    #pragma unroll
    for (int b = 0; b < 8; ++b) acc[b] = f4z();
    #pragma unroll
    for (int kk = 0; kk < 8; ++kk) {
        int k = g * 8 + kk;
        float4 wv = w3_4[(size_t)k * 128 + o4];
        #pragma unroll
        for (int b = 0; b < 8; ++b) {
            float hv = lds_h[b * 1024 + k];
            acc[b].x = fmaf(hv, wv.x, acc[b].x);
            acc[b].y = fmaf(hv, wv.y, acc[b].y);
            acc[b].z = fmaf(hv, wv.z, acc[b].z);
            acc[b].w = fmaf(hv, wv.w, acc[b].w);
        }
    }
    __syncthreads();
    #pragma unroll
    for (int b = 0; b < 8; ++b) buf[g * 32 + ol * 8 + b] = acc[b];
    __syncthreads();
    int u = t & 31, gg = t >> 5;
    float4 s = f4z();
    #pragma unroll
    for (int j = 0; j < 8; ++j) f4acc(s, buf[(gg * 8 + j) * 32 + u]);
    buf[gg * 256 + u] = s;
    __syncthreads();
    if (t < 32) {
        float4 v = f4z();
        #pragma unroll
        for (int gg2 = 0; gg2 < 16; ++gg2) f4acc(v, buf[gg2 * 256 + t]);
        int olr = t >> 3, b = t & 7;
        float4 bb = b3_4[oc * 4 + olr];
        v.x = fmaxf(v.x + bb.x, 0.f); v.y = fmaxf(v.y + bb.y, 0.f);
        v.z = fmaxf(v.z + bb.z, 0.f); v.w = fmaxf(v.w + bb.w, 0.f);
        h3_4[b * 128 + oc * 4 + olr] = v;
    }
}

// ============ L4: out = h3@w4+b4. 1 block x 512 ============
__global__ __launch_bounds__(512) void k_l4(
    const float* __restrict__ h3, const float* __restrict__ w4p,
    const float* __restrict__ b4p, float* __restrict__ out)
{
    __shared__ float h3s[4096];
    __shared__ float w4s[1024];
    __shared__ float red[8][8][2];
    int t = threadIdx.x;
    ((float4*)h3s)[t] = ((const float4*)h3)[t];
    ((float4*)h3s)[t + 512] = ((const float4*)h3)[t + 512];
    if (t < 256) ((float4*)w4s)[t] = ((const float4*)w4p)[t];
    __syncthreads();
    int w = t >> 6, lane = t & 63;
    #pragma unroll
    for (int b = 0; b < 8; ++b) {
        float hv = h3s[b * 512 + t];
        float v0 = hv * w4s[t * 2];
        float v1 = hv * w4s[t * 2 + 1];
        #pragma unroll
        for (int off = 32; off > 0; off >>= 1) {
            v0 += __shfl_xor(v0, off, 64);
            v1 += __shfl_xor(v1, off, 64);
        }
        if (lane == 0) { red[w][b][0] = v0; red[w][b][1] = v1; }
    }
    __syncthreads();
    if (t < 16) {
        int b = t >> 1, o = t & 1;
        float s = b4p[o];
        #pragma unroll
        for (int w2 = 0; w2 < 8; ++w2) s += red[w2][b][o];
        out[b * 2 + o] = s;
    }
}

extern "C" void kernel_launch(void* const* d_in, const int* in_sizes, int n_in,
                              void* d_out, int out_size, void* d_ws, size_t ws_size,
                              hipStream_t stream)
{
    const float* smi_tf   = (const float*)d_in[0];
    const float* pro_tf   = (const float*)d_in[1];
    const float* drug_gat = (const float*)d_in[2];
    const float* w_att    = (const float*)d_in[3];
    const float* b_att    = (const float*)d_in[4];
    const float* w1 = (const float*)d_in[5];
    const float* b1 = (const float*)d_in[6];
    const float* w2 = (const float*)d_in[7];
    const float* b2 = (const float*)d_in[8];
    const float* w3 = (const float*)d_in[9];
    const float* b3 = (const float*)d_in[10];
    const float* w4 = (const float*)d_in[11];
    const float* b4 = (const float*)d_in[12];
    float* out = (float*)d_out;

    float* ws = (float*)d_ws;
    float* smi_attss = ws;                    // 74240
    float* pro_att   = smi_attss + 74240;     // 512000
    float* smi_tfs   = pro_att + 512000;      // 74240
    float* pro_tfs   = smi_tfs + 74240;       // 512000
    float* x   = pro_tfs + 512000;            // 1024
    float* h1  = x + 1024;                    // 8192
    float* h2  = h1 + 8192;                   // 8192
    float* h3  = h2 + 8192;                   // 4096

    k_proj2<<<B * PROJ_BPB, 256, 0, stream>>>(smi_tf, pro_tf, drug_gat, w_att, b_att,
                                              smi_attss, pro_att);
    k_pair <<<PAIR_BLKS, 512, 0, stream>>>((const float4*)smi_attss, (const float4*)pro_att,
                                           smi_attss, pro_tf, w_att, b_att, smi_tfs, pro_tfs);
    k_pool <<<128, 512, 0, stream>>>((const float4*)smi_tfs, (const float4*)pro_tfs, x);
    k_l1   <<<16, 256, 0, stream>>>((const float4*)x, (const float4*)w1,
                                    (const float4*)b1, (float4*)h1);
    k_l2   <<<64, 512, 0, stream>>>((const float4*)h1, (const float4*)w2,
                                    (const float4*)b2, (float4*)h2);
    k_l3   <<<32, 512, 0, stream>>>((const float4*)h2, (const float4*)w3,
                                    (const float4*)b3, (float4*)h3);
    k_l4   <<<1, 512, 0, stream>>>(h3, w4, b4, out);
}